// Round 7
// baseline (482.003 us; speedup 1.0000x reference)
//
#include <hip/hip_runtime.h>
#include <math.h>

// Problem constants
#define B_   32
#define H_   512
#define W_   512
#define C_   3
#define M_   96          // B_*C_
#define NW_  263         // floor((512+15)/2)
#define NH_  263
#define DETPER 69169     // 263*263
#define DETTOT 207507    // 3*DETPER
#define DETSTRIDE 207508 // padded to multiple of 4 for float4 alignment
#define NVEC 51876       // DETTOT/4 (floor); tail = 3 elements
#define KRANK  103753u   // (DETTOT-1)/2, 0-based median rank

#define SXS 144          // sX row stride (floats)
#define CR  12           // sX chunk rows (46 = 12+12+12+10)

#define NBY   16         // hist kernels gridDim.y
#define SLOTS 4096       // NBY*256 capture slots per m
#define SCAP  24         // entries per slot (mean ~5.4, Poisson tail ~1e-10)

// db8 reconstruction filters (pre-derived; dec filters are reversed versions,
// and the reference's conv reduces to: ca[j] = sum_k xe[2j+k]*rec_lo[k])
__device__ __constant__ float RLO[16] = {
    0.05441584224308161f,  0.3128715909144659f,   0.6756307362980128f,
    0.5853546836548691f,  -0.015829105256023893f, -0.2840155429624281f,
    0.00047248457399797254f, 0.128747426620186f,  -0.01736930100202211f,
   -0.04408825393106472f,  0.013981027917015516f,  0.008746094047015655f,
   -0.00487035299301066f, -0.0003917403729959771f, 0.0006754494059985568f,
   -0.00011747678400228192f};
__device__ __constant__ float RHI[16] = {
   -0.00011747678400228192f, -0.0006754494059985568f, -0.0003917403729959771f,
    0.00487035299301066f,     0.008746094047015655f,  -0.013981027917015516f,
   -0.04408825393106472f,     0.01736930100202211f,    0.128747426620186f,
   -0.00047248457399797254f, -0.2840155429624281f,     0.015829105256023893f,
    0.5853546836548691f,     -0.6756307362980128f,     0.3128715909144659f,
   -0.05441584224308161f};

// Symmetric reflection of padded index q into [0, N)
__device__ __forceinline__ int refl(int q, int N) {
    if (q < 0)  return -q - 1;
    if (q >= N) return 2 * N - 1 - q;
    return q;
}

__device__ __forceinline__ float softthr(float v, float thr) {
    float a = fabsf(v) - thr;
    return a > 0.f ? copysignf(a, v) : 0.f;
}

// -------- zero-init for histogram region (no hipMemsetAsync in capture) --------
__global__ __launch_bounds__(256) void k_zero(unsigned* __restrict__ p, int n) {
    int i = blockIdx.x * 256 + threadIdx.x;
    if (i < n) p[i] = 0u;
}

// ---------------- Fused forward: row DWT + column DWT ----------------
// Swizzle v2 (factored): channels of a tile co-XCD (x-line sharing, round-6
// proven: FETCH 172->49 MB), but consecutive TILES round-robin across XCDs so
// det[m] writes stay spread over all 8 L2s (round-6's concentration regressed
// the hist scans ~40 us). lin = (T&7) + 8*(3*(T>>3)+c), bijective on 8160.
__global__ __launch_bounds__(256) void k_fwd(const float* __restrict__ x,
                                             float* __restrict__ ll,
                                             float* __restrict__ det) {
    __shared__ float sX[CR * SXS];                 // 6.75 KB, reused 4x
    __shared__ float sLO[46 * 64], sHI[46 * 64];   // 11.5 KB each
    const int lin = blockIdx.x + 96 * blockIdx.y + 480 * blockIdx.z;
    const int q = lin >> 3, s = lin & 7;
    const int c = q % 3, Thi = q / 3;              // Thi in [0,340)
    const int T = Thi * 8 + s;                     // tile-unit, 0..2719
    const int b = T / 85, r = T - 85 * b;          // 85 = 5 jw-tiles * 17 jh-tiles
    const int jw0 = (r % 5) * 64;
    const int jh0 = (r / 5) * 16;
    const int m = 3 * b + c;
    const int tid = threadIdx.x;
    const int prow0 = 2 * jh0 - 14, pcol0 = 2 * jw0 - 14;
    // chunked: stage CR padded-rows, row-DWT them, repeat (sX reused)
    for (int r0 = 0; r0 < 46; r0 += CR) {
        const int nr = (46 - r0) < CR ? (46 - r0) : CR;
        for (int l = tid; l < nr * 142; l += 256) {
            int rr = l / 142, cl = l - rr * 142;
            int h = refl(prow0 + r0 + rr, H_);
            int w = refl(pcol0 + cl, W_);
            sX[rr * SXS + cl] = x[((size_t)(b * H_ + h) * W_ + w) * C_ + c];
        }
        __syncthreads();
        for (int l = tid; l < nr * 64; l += 256) {
            int rr = l >> 6, j = l & 63;
            const float* px = &sX[rr * SXS + 2 * j];
            float al = 0.f, ah = 0.f;
#pragma unroll
            for (int k = 0; k < 16; ++k) {
                al = fmaf(px[k], RLO[k], al);
                ah = fmaf(px[k], RHI[k], ah);
            }
            sLO[(r0 + rr) * 64 + j] = al;
            sHI[(r0 + rr) * 64 + j] = ah;
        }
        __syncthreads();                           // sX reused next chunk
    }
    // column DWT: thread computes 4 consecutive jh (dy = 4*tg+d) at col tx,
    // loading the shared 22-row window once into registers.
    const int tx = tid & 63, tg = tid >> 6;
    const int jw = jw0 + tx;
    if (jw >= NW_) return;
    float vl[22], vh[22];
#pragma unroll
    for (int sr = 0; sr < 22; ++sr) {
        int row = 8 * tg + sr;                     // <= 45
        vl[sr] = sLO[row * 64 + tx];
        vh[sr] = sHI[row * 64 + tx];
    }
    float* llp = ll + (size_t)m * DETPER;
    float* dp  = det + (size_t)m * DETSTRIDE;
#pragma unroll
    for (int d = 0; d < 4; ++d) {
        int jh = jh0 + 4 * tg + d;
        if (jh >= NH_) continue;
        float a0 = 0.f, a1 = 0.f, a2 = 0.f, a3 = 0.f;
#pragma unroll
        for (int k = 0; k < 16; ++k) {
            float fl = vl[2 * d + k], fh = vh[2 * d + k];
            a0 = fmaf(fl, RLO[k], a0);
            a1 = fmaf(fl, RHI[k], a1);
            a2 = fmaf(fh, RLO[k], a2);
            a3 = fmaf(fh, RHI[k], a3);
        }
        size_t o = (size_t)jh * NW_ + jw;
        llp[o] = a0;                               // LL
        dp[o] = a1;                                // LH
        dp[DETPER + o] = a2;                       // HL
        dp[2 * DETPER + o] = a3;                   // HH
    }
}

// ---------------- Median: 3-pass radix histogram refinement over det ----------
__global__ __launch_bounds__(256) void k_hist1(const float* __restrict__ det,
                                               unsigned* __restrict__ hist) {
    __shared__ unsigned h[2048];
    const int tid = threadIdx.x, m = blockIdx.x;
    for (int i = tid; i < 2048; i += 256) h[i] = 0u;
    __syncthreads();
    const float* dp = det + (size_t)m * DETSTRIDE;
    const float4* dp4 = (const float4*)dp;
    const int stride = gridDim.y * 256;
    for (int v = blockIdx.y * 256 + tid; v < NVEC; v += stride) {
        float4 f = dp4[v];
        atomicAdd(&h[__float_as_uint(fabsf(f.x)) >> 21], 1u);
        atomicAdd(&h[__float_as_uint(fabsf(f.y)) >> 21], 1u);
        atomicAdd(&h[__float_as_uint(fabsf(f.z)) >> 21], 1u);
        atomicAdd(&h[__float_as_uint(fabsf(f.w)) >> 21], 1u);
    }
    if (blockIdx.y == 0 && tid < DETTOT - 4 * NVEC) {
        unsigned u = __float_as_uint(fabsf(dp[4 * NVEC + tid]));
        atomicAdd(&h[u >> 21], 1u);
    }
    __syncthreads();
    for (int i = tid; i < 2048; i += 256)
        if (h[i]) atomicAdd(&hist[m * 2048 + i], h[i]);
}

// hist2: scan + mid-11-bit histogram of selBin1 matches, and capture matches
// into per-THREAD slices with a REGISTER counter (no atomics, no ballot chain:
// rounds 3/4/5 showed LDS-counter, global-counter, and wave-ballot captures
// all serialize). Interleaved layout list[j*SLOTS + slot] -> coalesced in hist3.
// Overflow (> SCAP in one thread) sets ovf[m] -> hist3 takes exact full scan.
__global__ __launch_bounds__(256) void k_hist2(const float* __restrict__ det,
                                               const int* __restrict__ selBin1,
                                               unsigned* __restrict__ hist,
                                               unsigned* __restrict__ cnt,
                                               unsigned* __restrict__ ovf,
                                               unsigned* __restrict__ list,
                                               int docap) {
    __shared__ unsigned h[2048];
    const int tid = threadIdx.x, m = blockIdx.x, by = blockIdx.y;
    const unsigned target = (unsigned)selBin1[m];
    for (int i = tid; i < 2048; i += 256) h[i] = 0u;
    __syncthreads();
    const float* dp = det + (size_t)m * DETSTRIDE;
    const float4* dp4 = (const float4*)dp;
    const int stride = gridDim.y * 256;
    const unsigned slot = (unsigned)(by * 256 + tid);
    unsigned* const lst = list + (size_t)m * SLOTS * SCAP;
    unsigned mycnt = 0u;
    auto take = [&](unsigned u) {
        if ((u >> 21) == target) {
            atomicAdd(&h[(u >> 10) & 0x7FFu], 1u);
            if (docap) {
                if (mycnt < SCAP) lst[mycnt * SLOTS + slot] = u;  // fire-and-forget
                ++mycnt;
            }
        }
    };
    for (int v = by * 256 + tid; v < NVEC; v += stride) {
        float4 f = dp4[v];
        take(__float_as_uint(fabsf(f.x)));
        take(__float_as_uint(fabsf(f.y)));
        take(__float_as_uint(fabsf(f.z)));
        take(__float_as_uint(fabsf(f.w)));
    }
    if (by == 0 && tid < DETTOT - 4 * NVEC)
        take(__float_as_uint(fabsf(dp[4 * NVEC + tid])));
    if (docap) {
        cnt[m * SLOTS + slot] = mycnt;
        if (mycnt > SCAP) atomicOr(&ovf[m], 1u);   // never in practice
    }
    __syncthreads();
    for (int i = tid; i < 2048; i += 256)
        if (h[i]) atomicAdd(&hist[m * 2048 + i], h[i]);
}

// hist3: fast path — each thread replays its hist2 slice (coalesced stride-SLOTS
// reads, ~5 entries); exact full-scan fallback if overflow or capture disabled.
__global__ __launch_bounds__(256) void k_hist3(const float* __restrict__ det,
                                               const int* __restrict__ selBin1,
                                               const int* __restrict__ selBin2,
                                               const unsigned* __restrict__ cnt,
                                               const unsigned* __restrict__ ovf,
                                               const unsigned* __restrict__ list,
                                               int docap,
                                               unsigned* __restrict__ hist) {
    __shared__ unsigned h[1024];
    const int tid = threadIdx.x, m = blockIdx.x, by = blockIdx.y;
    for (int i = tid; i < 1024; i += 256) h[i] = 0u;
    __syncthreads();
    const bool fast = docap && (ovf[m] == 0u);     // uniform across m's blocks
    if (fast) {
        const unsigned b2 = (unsigned)selBin2[m];
        const unsigned slot = (unsigned)(by * 256 + tid);
        const unsigned n = cnt[m * SLOTS + slot];
        const unsigned* lst = list + (size_t)m * SLOTS * SCAP;
        for (unsigned j = 0; j < n; ++j) {
            unsigned u = lst[j * SLOTS + slot];
            if (((u >> 10) & 0x7FFu) == b2) atomicAdd(&h[u & 0x3FFu], 1u);
        }
    } else {
        const unsigned target = ((unsigned)selBin1[m] << 11) | (unsigned)selBin2[m];
        const float* dp = det + (size_t)m * DETSTRIDE;
        const float4* dp4 = (const float4*)dp;
        const int stride = gridDim.y * 256;
        for (int v = by * 256 + tid; v < NVEC; v += stride) {
            float4 f = dp4[v];
            unsigned a = __float_as_uint(fabsf(f.x));
            unsigned b = __float_as_uint(fabsf(f.y));
            unsigned c = __float_as_uint(fabsf(f.z));
            unsigned d = __float_as_uint(fabsf(f.w));
            if ((a >> 10) == target) atomicAdd(&h[a & 0x3FFu], 1u);
            if ((b >> 10) == target) atomicAdd(&h[b & 0x3FFu], 1u);
            if ((c >> 10) == target) atomicAdd(&h[c & 0x3FFu], 1u);
            if ((d >> 10) == target) atomicAdd(&h[d & 0x3FFu], 1u);
        }
        if (by == 0 && tid < DETTOT - 4 * NVEC) {
            unsigned u = __float_as_uint(fabsf(dp[4 * NVEC + tid]));
            if ((u >> 10) == target) atomicAdd(&h[u & 0x3FFu], 1u);
        }
    }
    __syncthreads();
    for (int i = tid; i < 1024; i += 256)
        if (h[i]) atomicAdd(&hist[m * 1024 + i], h[i]);
}

// Cooperative select: find bin of LDS histogram (nb multiple of 256) containing `rank`
__device__ int histSelect(unsigned* hist, int nb, unsigned rank, unsigned* rem) {
    __shared__ unsigned ps[256];
    __shared__ int s_bin;
    __shared__ unsigned s_rem;
    const int tid = threadIdx.x;
    if (tid == 0) { s_bin = 0; s_rem = 0; }      // deterministic fallback
    const int per = nb >> 8;
    unsigned s = 0;
    for (int i = 0; i < per; ++i) s += hist[tid * per + i];
    ps[tid] = s;
    __syncthreads();
    for (int off = 1; off < 256; off <<= 1) {
        unsigned v = ps[tid];
        unsigned add = (tid >= off) ? ps[tid - off] : 0u;
        __syncthreads();
        ps[tid] = v + add;
        __syncthreads();
    }
    unsigned incl = ps[tid], excl = incl - s;
    if (rank >= excl && rank < incl) {
        unsigned cum = excl;
        for (int i = 0; i < per; ++i) {
            unsigned c = hist[tid * per + i];
            if (cum + c > rank) { s_bin = tid * per + i; s_rem = rank - cum; break; }
            cum += c;
        }
    }
    __syncthreads();
    int rbin = s_bin;
    unsigned rr = s_rem;
    __syncthreads();   // protect shared reuse across calls
    *rem = rr;
    return rbin;
}

__global__ __launch_bounds__(256) void k_sel2048(const unsigned* __restrict__ hist,
                                                 const unsigned* __restrict__ rankIn, // null => KRANK
                                                 int* __restrict__ selBin,
                                                 unsigned* __restrict__ rankOut) {
    __shared__ unsigned h[2048];
    const int m = blockIdx.x, tid = threadIdx.x;
    for (int i = tid; i < 2048; i += 256) h[i] = hist[m * 2048 + i];
    __syncthreads();
    unsigned rank = rankIn ? rankIn[m] : KRANK;
    unsigned rem;
    int bin = histSelect(h, 2048, rank, &rem);
    if (tid == 0) { selBin[m] = bin; rankOut[m] = rem; }
}

__global__ __launch_bounds__(256) void k_sel3(const unsigned* __restrict__ hist,
                                              const unsigned* __restrict__ rankIn,
                                              const int* __restrict__ selBin1,
                                              const int* __restrict__ selBin2,
                                              float* __restrict__ tval) {
    __shared__ unsigned h[1024];
    const int m = blockIdx.x, tid = threadIdx.x;
    for (int i = tid; i < 1024; i += 256) h[i] = hist[m * 1024 + i];
    __syncthreads();
    unsigned rem;
    int low = histSelect(h, 1024, rankIn[m], &rem);
    if (tid == 0) {
        unsigned bits = ((unsigned)selBin1[m] << 21) | ((unsigned)selBin2[m] << 10) | (unsigned)low;
        double med = (double)__uint_as_float(bits);
        // t = median/0.6745 * sqrt(2*ln(512*512))
        tval[m] = (float)(med / 0.6745 * 4.995327667046959);
    }
}

// ---------------- Fused inverse: soft-threshold + column IDWT + row IDWT ------
// v3 body + factored swizzle: channels of a tile co-XCD (NHWC write-combining),
// tiles spread across XCDs (det reads match k_fwd's spread write distribution).
__global__ __launch_bounds__(256) void k_inv(const float* __restrict__ ll,
                                             const float* __restrict__ det,
                                             const float* __restrict__ tval,
                                             float* __restrict__ out) {
    __shared__ float sLL[23 * 40], sLH[23 * 40], sHL[23 * 40], sHH[23 * 40];
    __shared__ float sRL[32 * 40], sRH[32 * 40];
    const int lin = blockIdx.x + 96 * blockIdx.y + 768 * blockIdx.z;
    const int qq = lin >> 3, s = lin & 7;
    const int c = qq % 3, Uhi = qq / 3;           // Uhi in [0,512)
    const int U = Uhi * 8 + s;                    // 0..4095
    const int b = U >> 7, r = U & 127;            // 128 = 8 w-tiles * 16 t-tiles
    const int w0 = (r & 7) * 64;
    const int t0 = (r >> 3) * 32;
    const int m = 3 * b + c;
    const int tid = threadIdx.x;
    const float thr = tval[m];
    const int jW0 = w0 >> 1, s0 = t0 >> 1;
    const float* llp = ll + (size_t)m * DETPER;
    const float* dp  = det + (size_t)m * DETSTRIDE;
    for (int l = tid; l < 23 * 39; l += 256) {
        int rr = l / 39, cc = l - rr * 39;
        size_t o = (size_t)(s0 + rr) * NW_ + (jW0 + cc);
        int li = rr * 40 + cc;
        sLL[li] = llp[o];
        sLH[li] = softthr(dp[o], thr);
        sHL[li] = softthr(dp[DETPER + o], thr);
        sHH[li] = softthr(dp[2 * DETPER + o], thr);
    }
    __syncthreads();
    // column IDWT: item (s2 in [0,16), q in [0,10)) -> output rows 2s2,2s2+1,
    // cols 4q..4q+3. Source rows s2..s2+7 (<=22); col 39 never read downstream.
    for (int l = tid; l < 160; l += 256) {
        int s2 = l / 10, q = l - 10 * (l / 10);
        float4 aL0 = make_float4(0.f, 0.f, 0.f, 0.f), aL1 = aL0, aH0 = aL0, aH1 = aL0;
#pragma unroll
        for (int a = 0; a < 8; ++a) {
            int li = (s2 + 7 - a) * 40 + 4 * q;
            float4 vLL = *(const float4*)&sLL[li];
            float4 vLH = *(const float4*)&sLH[li];
            float4 vHL = *(const float4*)&sHL[li];
            float4 vHH = *(const float4*)&sHH[li];
            float w00 = RLO[2 * a],     h00 = RHI[2 * a];       // parity r=0
            float w01 = RLO[2 * a + 1], h01 = RHI[2 * a + 1];   // parity r=1
            aL0.x = fmaf(vLL.x, w00, fmaf(vLH.x, h00, aL0.x));
            aL0.y = fmaf(vLL.y, w00, fmaf(vLH.y, h00, aL0.y));
            aL0.z = fmaf(vLL.z, w00, fmaf(vLH.z, h00, aL0.z));
            aL0.w = fmaf(vLL.w, w00, fmaf(vLH.w, h00, aL0.w));
            aL1.x = fmaf(vLL.x, w01, fmaf(vLH.x, h01, aL1.x));
            aL1.y = fmaf(vLL.y, w01, fmaf(vLH.y, h01, aL1.y));
            aL1.z = fmaf(vLL.z, w01, fmaf(vLH.z, h01, aL1.z));
            aL1.w = fmaf(vLL.w, w01, fmaf(vLH.w, h01, aL1.w));
            aH0.x = fmaf(vHL.x, w00, fmaf(vHH.x, h00, aH0.x));
            aH0.y = fmaf(vHL.y, w00, fmaf(vHH.y, h00, aH0.y));
            aH0.z = fmaf(vHL.z, w00, fmaf(vHH.z, h00, aH0.z));
            aH0.w = fmaf(vHL.w, w00, fmaf(vHH.w, h00, aH0.w));
            aH1.x = fmaf(vHL.x, w01, fmaf(vHH.x, h01, aH1.x));
            aH1.y = fmaf(vHL.y, w01, fmaf(vHH.y, h01, aH1.y));
            aH1.z = fmaf(vHL.z, w01, fmaf(vHH.z, h01, aH1.z));
            aH1.w = fmaf(vHL.w, w01, fmaf(vHH.w, h01, aH1.w));
        }
        *(float4*)&sRL[(2 * s2) * 40 + 4 * q]     = aL0;
        *(float4*)&sRL[(2 * s2 + 1) * 40 + 4 * q] = aL1;
        *(float4*)&sRH[(2 * s2) * 40 + 4 * q]     = aH0;
        *(float4*)&sRH[(2 * s2 + 1) * 40 + 4 * q] = aH1;
    }
    __syncthreads();
    // row IDWT + NHWC store: thread (tr = tid>>3, jg = tid&7) produces the 8
    // outputs wloc = 8jg..8jg+7 from words [4jg, 4jg+10] of sRL/sRH (3 b128 each).
    {
        const int tr = tid >> 3, jg = tid & 7;
        const float4* pl = (const float4*)&sRL[tr * 40 + 4 * jg];  // 16B aligned
        const float4* ph = (const float4*)&sRH[tr * 40 + 4 * jg];
        float4 L0 = pl[0], L1 = pl[1], L2 = pl[2];
        float4 K0 = ph[0], K1 = ph[1], K2 = ph[2];
        float rl[12] = {L0.x,L0.y,L0.z,L0.w, L1.x,L1.y,L1.z,L1.w, L2.x,L2.y,L2.z,L2.w};
        float rh[12] = {K0.x,K0.y,K0.z,K0.w, K1.x,K1.y,K1.z,K1.w, K2.x,K2.y,K2.z,K2.w};
        size_t obase = ((size_t)(b * H_ + (t0 + tr)) * W_ + (w0 + 8 * jg)) * C_ + c;
#pragma unroll
        for (int u2 = 0; u2 < 4; ++u2) {
#pragma unroll
            for (int rp = 0; rp < 2; ++rp) {
                float acc = 0.f;
#pragma unroll
                for (int a = 0; a < 8; ++a) {
                    int sdx = u2 + 7 - a;        // in [u2, u2+7] subset of [0,10]
                    acc = fmaf(rl[sdx], RLO[2 * a + rp], fmaf(rh[sdx], RHI[2 * a + rp], acc));
                }
                out[obase + (size_t)(2 * u2 + rp) * C_] = acc;
            }
        }
    }
}

extern "C" void kernel_launch(void* const* d_in, const int* in_sizes, int n_in,
                              void* d_out, int out_size, void* d_ws, size_t ws_size,
                              hipStream_t stream) {
    const float* x = (const float*)d_in[0];
    float* out = (float*)d_out;

    char* ws = (char*)d_ws;
    float* ll  = (float*)ws; ws += (size_t)M_ * DETPER * 4;     // 26.56 MB
    float* det = (float*)ws; ws += (size_t)M_ * DETSTRIDE * 4;  // 79.68 MB  [m][{lh,hl,hh}][DETPER]
    unsigned* hist1 = (unsigned*)ws; ws += (size_t)M_ * 2048 * 4;
    unsigned* hist2 = (unsigned*)ws; ws += (size_t)M_ * 2048 * 4;
    unsigned* hist3 = (unsigned*)ws; ws += (size_t)M_ * 1024 * 4;
    unsigned* ovf   = (unsigned*)ws;   ws += M_ * 4;            // contiguous with hists (zeroed)
    int*      selBin1 = (int*)ws;      ws += M_ * 4;
    int*      selBin2 = (int*)ws;      ws += M_ * 4;
    unsigned* rank1   = (unsigned*)ws; ws += M_ * 4;
    unsigned* rank2   = (unsigned*)ws; ws += M_ * 4;
    float*    tval    = (float*)ws;    ws += M_ * 4;
    unsigned* cnt     = (unsigned*)ws; ws += (size_t)M_ * SLOTS * 4;        // 1.5 MB
    unsigned* list    = (unsigned*)ws; ws += (size_t)M_ * SLOTS * SCAP * 4; // 37.75 MB
    // total ws usage: ~147 MB
    const int docap = (ws_size >= (size_t)(ws - (char*)d_ws)) ? 1 : 0;

    const int histWords = M_ * (2048 + 2048 + 1024) + M_;       // hists + ovf
    k_zero   <<<dim3((histWords + 255) / 256), 256, 0, stream>>>(hist1, histWords);
    k_fwd    <<<dim3(M_, 5, 17),  256, 0, stream>>>(x, ll, det);
    k_hist1  <<<dim3(M_, NBY),    256, 0, stream>>>(det, hist1);
    k_sel2048<<<dim3(M_),         256, 0, stream>>>(hist1, nullptr, selBin1, rank1);
    k_hist2  <<<dim3(M_, NBY),    256, 0, stream>>>(det, selBin1, hist2, cnt, ovf, list, docap);
    k_sel2048<<<dim3(M_),         256, 0, stream>>>(hist2, rank1, selBin2, rank2);
    k_hist3  <<<dim3(M_, NBY),    256, 0, stream>>>(det, selBin1, selBin2, cnt, ovf, list, docap, hist3);
    k_sel3   <<<dim3(M_),         256, 0, stream>>>(hist3, rank2, selBin1, selBin2, tval);
    k_inv    <<<dim3(M_, 8, 16),  256, 0, stream>>>(ll, det, tval, out);
}

// Round 8
// 447.197 us; speedup vs baseline: 1.0778x; 1.0778x over previous
//
#include <hip/hip_runtime.h>
#include <math.h>

// Problem constants
#define B_   32
#define H_   512
#define W_   512
#define C_   3
#define M_   96          // B_*C_
#define NW_  263         // floor((512+15)/2)
#define NH_  263
#define DETPER 69169     // 263*263
#define DETTOT 207507    // 3*DETPER
#define DETSTRIDE 207508 // padded to multiple of 4 for float4 alignment
#define NVEC 51876       // DETTOT/4 (floor); tail = 3 elements
#define KRANK  103753u   // (DETTOT-1)/2, 0-based median rank

#define SXS 144          // sX row stride (floats)
#define CR  16           // sX chunk rows (46 = 16+16+14); sX 9216 B >= 8 KB hist alias

#define NBY   16         // hist kernels gridDim.y
#define SLOTS 4096       // NBY*256 capture slots per m
#define SCAP  24         // entries per slot (mean ~4, Poisson tail ~1e-10)

// db8 reconstruction filters (pre-derived; dec filters are reversed versions,
// and the reference's conv reduces to: ca[j] = sum_k xe[2j+k]*rec_lo[k])
__device__ __constant__ float RLO[16] = {
    0.05441584224308161f,  0.3128715909144659f,   0.6756307362980128f,
    0.5853546836548691f,  -0.015829105256023893f, -0.2840155429624281f,
    0.00047248457399797254f, 0.128747426620186f,  -0.01736930100202211f,
   -0.04408825393106472f,  0.013981027917015516f,  0.008746094047015655f,
   -0.00487035299301066f, -0.0003917403729959771f, 0.0006754494059985568f,
   -0.00011747678400228192f};
__device__ __constant__ float RHI[16] = {
   -0.00011747678400228192f, -0.0006754494059985568f, -0.0003917403729959771f,
    0.00487035299301066f,     0.008746094047015655f,  -0.013981027917015516f,
   -0.04408825393106472f,     0.01736930100202211f,    0.128747426620186f,
   -0.00047248457399797254f, -0.2840155429624281f,     0.015829105256023893f,
    0.5853546836548691f,     -0.6756307362980128f,     0.3128715909144659f,
   -0.05441584224308161f};

// Symmetric reflection of padded index q into [0, N)
__device__ __forceinline__ int refl(int q, int N) {
    if (q < 0)  return -q - 1;
    if (q >= N) return 2 * N - 1 - q;
    return q;
}

__device__ __forceinline__ float softthr(float v, float thr) {
    float a = fabsf(v) - thr;
    return a > 0.f ? copysignf(a, v) : 0.f;
}

// -------- zero-init for histogram region (no hipMemsetAsync in capture) --------
__global__ __launch_bounds__(256) void k_zero(unsigned* __restrict__ p, int n) {
    int i = blockIdx.x * 256 + threadIdx.x;
    if (i < n) p[i] = 0u;
}

// ---------------- Fused forward: row DWT + column DWT + hist1 ----------------
// Round-2 structure (natural block order — all XCD swizzles measured net-negative).
// New vs round-2:
//  (1) light path for the last jw-tile (jw0=256: only 7/64 cols valid — stage 28
//      cols and row-DWT 7 instead of full 142/64; removes ~17% of total work).
//  (2) hist1 fused: LDS histogram ALIASED onto sX (dead after last chunk; CR=16
//      makes sX 9216 B >= 8192 B) -> zero extra LDS, occupancy stays 5 blocks/CU.
__global__ __launch_bounds__(256) void k_fwd(const float* __restrict__ x,
                                             float* __restrict__ ll,
                                             float* __restrict__ det,
                                             unsigned* __restrict__ hist) {
    __shared__ float sX[CR * SXS];                 // 9.0 KB, reused 3x, then hist alias
    __shared__ float sLO[46 * 64], sHI[46 * 64];   // 11.5 KB each; total exactly 32 KB
    unsigned* hh = (unsigned*)sX;                  // 2048-bin hist1 alias
    const int m   = blockIdx.x;
    const int jw0 = blockIdx.y * 64;               // 5 tiles (last is light)
    const int jh0 = blockIdx.z * 16;               // 17 tiles
    const int b = m / 3, c = m - 3 * (m / 3);
    const int tid = threadIdx.x;
    const int prow0 = 2 * jh0 - 14, pcol0 = 2 * jw0 - 14;
    const bool light = (jw0 + 64 > NW_);           // blockIdx.y == 4 only
    if (!light) {
        for (int r0 = 0; r0 < 46; r0 += CR) {
            const int nr = (46 - r0) < CR ? (46 - r0) : CR;
            for (int l = tid; l < nr * 142; l += 256) {
                int rr = l / 142, cl = l - rr * 142;
                int h = refl(prow0 + r0 + rr, H_);
                int w = refl(pcol0 + cl, W_);
                sX[rr * SXS + cl] = x[((size_t)(b * H_ + h) * W_ + w) * C_ + c];
            }
            __syncthreads();
            for (int l = tid; l < nr * 64; l += 256) {
                int rr = l >> 6, j = l & 63;
                const float* px = &sX[rr * SXS + 2 * j];
                float al = 0.f, ah = 0.f;
#pragma unroll
                for (int k = 0; k < 16; ++k) {
                    al = fmaf(px[k], RLO[k], al);
                    ah = fmaf(px[k], RHI[k], ah);
                }
                sLO[(r0 + rr) * 64 + j] = al;
                sHI[(r0 + rr) * 64 + j] = ah;
            }
            __syncthreads();                       // sX reused next chunk
        }
    } else {
        // light: 7 valid cols -> stage 2*7+14=28 padded cols, row-DWT 7 j's
        for (int r0 = 0; r0 < 46; r0 += CR) {
            const int nr = (46 - r0) < CR ? (46 - r0) : CR;
            for (int l = tid; l < nr * 28; l += 256) {
                int rr = l / 28, cl = l - rr * 28;
                int h = refl(prow0 + r0 + rr, H_);
                int w = refl(pcol0 + cl, W_);
                sX[rr * SXS + cl] = x[((size_t)(b * H_ + h) * W_ + w) * C_ + c];
            }
            __syncthreads();
            for (int l = tid; l < nr * 7; l += 256) {
                int rr = l / 7, j = l - 7 * (l / 7);
                const float* px = &sX[rr * SXS + 2 * j];
                float al = 0.f, ah = 0.f;
#pragma unroll
                for (int k = 0; k < 16; ++k) {
                    al = fmaf(px[k], RLO[k], al);
                    ah = fmaf(px[k], RHI[k], ah);
                }
                sLO[(r0 + rr) * 64 + j] = al;
                sHI[(r0 + rr) * 64 + j] = ah;
            }
            __syncthreads();
        }
    }
    // sX dead -> zero the aliased hist bins
    for (int i = tid; i < 2048; i += 256) hh[i] = 0u;
    __syncthreads();
    // column DWT: thread computes 4 consecutive jh at col tx; window in registers.
    const int tx = tid & 63, tg = tid >> 6;
    const int jw = jw0 + tx;
    const bool vw = (jw < NW_);                    // NO early return (barriers below)
    float vl[22], vh[22];
#pragma unroll
    for (int s = 0; s < 22; ++s) {
        int row = 8 * tg + s;                      // <= 45
        vl[s] = sLO[row * 64 + tx];
        vh[s] = sHI[row * 64 + tx];
    }
    float* llp = ll + (size_t)m * DETPER;
    float* dp  = det + (size_t)m * DETSTRIDE;
#pragma unroll
    for (int d = 0; d < 4; ++d) {
        int jh = jh0 + 4 * tg + d;
        float a0 = 0.f, a1 = 0.f, a2 = 0.f, a3 = 0.f;
#pragma unroll
        for (int k = 0; k < 16; ++k) {
            float fl = vl[2 * d + k], fh = vh[2 * d + k];
            a0 = fmaf(fl, RLO[k], a0);
            a1 = fmaf(fl, RHI[k], a1);
            a2 = fmaf(fh, RLO[k], a2);
            a3 = fmaf(fh, RHI[k], a3);
        }
        if (vw && jh < NH_) {
            size_t o = (size_t)jh * NW_ + jw;
            llp[o] = a0;                           // LL
            dp[o] = a1;                            // LH
            dp[DETPER + o] = a2;                   // HL
            dp[2 * DETPER + o] = a3;               // HH
            atomicAdd(&hh[__float_as_uint(fabsf(a1)) >> 21], 1u);
            atomicAdd(&hh[__float_as_uint(fabsf(a2)) >> 21], 1u);
            atomicAdd(&hh[__float_as_uint(fabsf(a3)) >> 21], 1u);
        }
    }
    __syncthreads();
    for (int i = tid; i < 2048; i += 256)
        if (hh[i]) atomicAdd(&hist[m * 2048 + i], hh[i]);
}

// hist2: scan + mid-11-bit histogram of selBin1 matches, and capture matches
// into per-THREAD slices with a REGISTER counter (no atomics, no ballot chain —
// rounds 3/4/5 showed LDS-counter, global-counter, wave-ballot all serialize).
// Interleaved layout list[j*SLOTS + slot] -> coalesced. Overflow -> exact fallback.
__global__ __launch_bounds__(256) void k_hist2(const float* __restrict__ det,
                                               const int* __restrict__ selBin1,
                                               unsigned* __restrict__ hist,
                                               unsigned* __restrict__ cnt,
                                               unsigned* __restrict__ ovf,
                                               unsigned* __restrict__ list,
                                               int docap) {
    __shared__ unsigned h[2048];
    const int tid = threadIdx.x, m = blockIdx.x, by = blockIdx.y;
    const unsigned target = (unsigned)selBin1[m];
    for (int i = tid; i < 2048; i += 256) h[i] = 0u;
    __syncthreads();
    const float* dp = det + (size_t)m * DETSTRIDE;
    const float4* dp4 = (const float4*)dp;
    const int stride = gridDim.y * 256;
    const unsigned slot = (unsigned)(by * 256 + tid);
    unsigned* const lst = list + (size_t)m * SLOTS * SCAP;
    unsigned mycnt = 0u;
    auto take = [&](unsigned u) {
        if ((u >> 21) == target) {
            atomicAdd(&h[(u >> 10) & 0x7FFu], 1u);
            if (docap) {
                if (mycnt < SCAP) lst[mycnt * SLOTS + slot] = u;  // fire-and-forget
                ++mycnt;
            }
        }
    };
    for (int v = by * 256 + tid; v < NVEC; v += stride) {
        float4 f = dp4[v];
        take(__float_as_uint(fabsf(f.x)));
        take(__float_as_uint(fabsf(f.y)));
        take(__float_as_uint(fabsf(f.z)));
        take(__float_as_uint(fabsf(f.w)));
    }
    if (by == 0 && tid < DETTOT - 4 * NVEC)
        take(__float_as_uint(fabsf(dp[4 * NVEC + tid])));
    if (docap) {
        cnt[m * SLOTS + slot] = mycnt;
        if (mycnt > SCAP) atomicOr(&ovf[m], 1u);   // ~never in practice
    }
    __syncthreads();
    for (int i = tid; i < 2048; i += 256)
        if (h[i]) atomicAdd(&hist[m * 2048 + i], h[i]);
}

// hist3: fast path — each thread replays its hist2 slice (~4 coalesced entries);
// exact full-scan fallback if overflow or capture disabled.
__global__ __launch_bounds__(256) void k_hist3(const float* __restrict__ det,
                                               const int* __restrict__ selBin1,
                                               const int* __restrict__ selBin2,
                                               const unsigned* __restrict__ cnt,
                                               const unsigned* __restrict__ ovf,
                                               const unsigned* __restrict__ list,
                                               int docap,
                                               unsigned* __restrict__ hist) {
    __shared__ unsigned h[1024];
    const int tid = threadIdx.x, m = blockIdx.x, by = blockIdx.y;
    for (int i = tid; i < 1024; i += 256) h[i] = 0u;
    __syncthreads();
    const bool fast = docap && (ovf[m] == 0u);     // uniform across m's blocks
    if (fast) {
        const unsigned b2 = (unsigned)selBin2[m];
        const unsigned slot = (unsigned)(by * 256 + tid);
        const unsigned n = cnt[m * SLOTS + slot];
        const unsigned* lst = list + (size_t)m * SLOTS * SCAP;
        for (unsigned j = 0; j < n; ++j) {
            unsigned u = lst[j * SLOTS + slot];
            if (((u >> 10) & 0x7FFu) == b2) atomicAdd(&h[u & 0x3FFu], 1u);
        }
    } else {
        const unsigned target = ((unsigned)selBin1[m] << 11) | (unsigned)selBin2[m];
        const float* dp = det + (size_t)m * DETSTRIDE;
        const float4* dp4 = (const float4*)dp;
        const int stride = gridDim.y * 256;
        for (int v = by * 256 + tid; v < NVEC; v += stride) {
            float4 f = dp4[v];
            unsigned a = __float_as_uint(fabsf(f.x));
            unsigned b = __float_as_uint(fabsf(f.y));
            unsigned c = __float_as_uint(fabsf(f.z));
            unsigned d = __float_as_uint(fabsf(f.w));
            if ((a >> 10) == target) atomicAdd(&h[a & 0x3FFu], 1u);
            if ((b >> 10) == target) atomicAdd(&h[b & 0x3FFu], 1u);
            if ((c >> 10) == target) atomicAdd(&h[c & 0x3FFu], 1u);
            if ((d >> 10) == target) atomicAdd(&h[d & 0x3FFu], 1u);
        }
        if (by == 0 && tid < DETTOT - 4 * NVEC) {
            unsigned u = __float_as_uint(fabsf(dp[4 * NVEC + tid]));
            if ((u >> 10) == target) atomicAdd(&h[u & 0x3FFu], 1u);
        }
    }
    __syncthreads();
    for (int i = tid; i < 1024; i += 256)
        if (h[i]) atomicAdd(&hist[m * 1024 + i], h[i]);
}

// Cooperative select: find bin of LDS histogram (nb multiple of 256) containing `rank`
__device__ int histSelect(unsigned* hist, int nb, unsigned rank, unsigned* rem) {
    __shared__ unsigned ps[256];
    __shared__ int s_bin;
    __shared__ unsigned s_rem;
    const int tid = threadIdx.x;
    if (tid == 0) { s_bin = 0; s_rem = 0; }      // deterministic fallback
    const int per = nb >> 8;
    unsigned s = 0;
    for (int i = 0; i < per; ++i) s += hist[tid * per + i];
    ps[tid] = s;
    __syncthreads();
    for (int off = 1; off < 256; off <<= 1) {
        unsigned v = ps[tid];
        unsigned add = (tid >= off) ? ps[tid - off] : 0u;
        __syncthreads();
        ps[tid] = v + add;
        __syncthreads();
    }
    unsigned incl = ps[tid], excl = incl - s;
    if (rank >= excl && rank < incl) {
        unsigned cum = excl;
        for (int i = 0; i < per; ++i) {
            unsigned c = hist[tid * per + i];
            if (cum + c > rank) { s_bin = tid * per + i; s_rem = rank - cum; break; }
            cum += c;
        }
    }
    __syncthreads();
    int rbin = s_bin;
    unsigned rr = s_rem;
    __syncthreads();   // protect shared reuse across calls
    *rem = rr;
    return rbin;
}

__global__ __launch_bounds__(256) void k_sel2048(const unsigned* __restrict__ hist,
                                                 const unsigned* __restrict__ rankIn, // null => KRANK
                                                 int* __restrict__ selBin,
                                                 unsigned* __restrict__ rankOut) {
    __shared__ unsigned h[2048];
    const int m = blockIdx.x, tid = threadIdx.x;
    for (int i = tid; i < 2048; i += 256) h[i] = hist[m * 2048 + i];
    __syncthreads();
    unsigned rank = rankIn ? rankIn[m] : KRANK;
    unsigned rem;
    int bin = histSelect(h, 2048, rank, &rem);
    if (tid == 0) { selBin[m] = bin; rankOut[m] = rem; }
}

__global__ __launch_bounds__(256) void k_sel3(const unsigned* __restrict__ hist,
                                              const unsigned* __restrict__ rankIn,
                                              const int* __restrict__ selBin1,
                                              const int* __restrict__ selBin2,
                                              float* __restrict__ tval) {
    __shared__ unsigned h[1024];
    const int m = blockIdx.x, tid = threadIdx.x;
    for (int i = tid; i < 1024; i += 256) h[i] = hist[m * 1024 + i];
    __syncthreads();
    unsigned rem;
    int low = histSelect(h, 1024, rankIn[m], &rem);
    if (tid == 0) {
        unsigned bits = ((unsigned)selBin1[m] << 21) | ((unsigned)selBin2[m] << 10) | (unsigned)low;
        double med = (double)__uint_as_float(bits);
        // t = median/0.6745 * sqrt(2*ln(512*512))
        tval[m] = (float)(med / 0.6745 * 4.995327667046959);
    }
}

// ---------------- Fused inverse: soft-threshold + column IDWT + row IDWT ------
// Round-0/round-2 body verbatim, natural block order (all swizzles regressed it).
__global__ __launch_bounds__(256) void k_inv(const float* __restrict__ ll,
                                             const float* __restrict__ det,
                                             const float* __restrict__ tval,
                                             float* __restrict__ out) {
    __shared__ float sLL[23 * 40], sLH[23 * 40], sHL[23 * 40], sHH[23 * 40];
    __shared__ float sRL[32 * 40], sRH[32 * 40];
    const int m  = blockIdx.x;                   // channels adjacent in dispatch
    const int w0 = blockIdx.y * 64;              // 8 tiles
    const int t0 = blockIdx.z * 32;              // 16 tiles
    const int b = m / 3, c = m - 3 * (m / 3);
    const int tid = threadIdx.x;
    const float thr = tval[m];
    const int jW0 = w0 >> 1, s0 = t0 >> 1;
    const float* llp = ll + (size_t)m * DETPER;
    const float* dp  = det + (size_t)m * DETSTRIDE;
    for (int l = tid; l < 23 * 39; l += 256) {
        int rr = l / 39, cc = l - rr * 39;
        size_t o = (size_t)(s0 + rr) * NW_ + (jW0 + cc);
        int li = rr * 40 + cc;
        sLL[li] = llp[o];
        sLH[li] = softthr(dp[o], thr);
        sHL[li] = softthr(dp[DETPER + o], thr);
        sHH[li] = softthr(dp[2 * DETPER + o], thr);
    }
    __syncthreads();
    // column IDWT: rl/rh rows t0..t0+31 at 39 jW cols
    for (int l = tid; l < 32 * 39; l += 256) {
        int tr = l / 39, cc = l - tr * 39;
        int srow = tr >> 1, r = tr & 1;
        float aL = 0.f, aH = 0.f;
#pragma unroll
        for (int a = 0; a < 8; ++a) {
            int li = (srow + 7 - a) * 40 + cc;
            float wl = RLO[2 * a + r], wh = RHI[2 * a + r];
            aL = fmaf(sLL[li], wl, fmaf(sLH[li], wh, aL));
            aH = fmaf(sHL[li], wl, fmaf(sHH[li], wh, aH));
        }
        sRL[tr * 40 + cc] = aL;
        sRH[tr * 40 + cc] = aH;
    }
    __syncthreads();
    // row IDWT + NHWC store
    for (int l = tid; l < 32 * 64; l += 256) {
        int tr = l >> 6, wloc = l & 63;
        int r = wloc & 1, jb = (wloc >> 1) + 7;  // local col index base, in [7,38]
        float acc = 0.f;
#pragma unroll
        for (int a = 0; a < 8; ++a) {
            int li = tr * 40 + jb - a;
            acc = fmaf(sRL[li], RLO[2 * a + r], fmaf(sRH[li], RHI[2 * a + r], acc));
        }
        out[((size_t)(b * H_ + (t0 + tr)) * W_ + (w0 + wloc)) * C_ + c] = acc;
    }
}

extern "C" void kernel_launch(void* const* d_in, const int* in_sizes, int n_in,
                              void* d_out, int out_size, void* d_ws, size_t ws_size,
                              hipStream_t stream) {
    const float* x = (const float*)d_in[0];
    float* out = (float*)d_out;

    char* ws = (char*)d_ws;
    float* ll  = (float*)ws; ws += (size_t)M_ * DETPER * 4;     // 26.56 MB
    float* det = (float*)ws; ws += (size_t)M_ * DETSTRIDE * 4;  // 79.68 MB  [m][{lh,hl,hh}][DETPER]
    unsigned* hist1 = (unsigned*)ws; ws += (size_t)M_ * 2048 * 4;
    unsigned* hist2 = (unsigned*)ws; ws += (size_t)M_ * 2048 * 4;
    unsigned* hist3 = (unsigned*)ws; ws += (size_t)M_ * 1024 * 4;
    unsigned* ovf   = (unsigned*)ws;   ws += M_ * 4;            // contiguous with hists (zeroed)
    int*      selBin1 = (int*)ws;      ws += M_ * 4;
    int*      selBin2 = (int*)ws;      ws += M_ * 4;
    unsigned* rank1   = (unsigned*)ws; ws += M_ * 4;
    unsigned* rank2   = (unsigned*)ws; ws += M_ * 4;
    float*    tval    = (float*)ws;    ws += M_ * 4;
    unsigned* cnt     = (unsigned*)ws; ws += (size_t)M_ * SLOTS * 4;        // 1.5 MB
    unsigned* list    = (unsigned*)ws; ws += (size_t)M_ * SLOTS * SCAP * 4; // 37.75 MB
    // total ws usage: ~147 MB
    const int docap = (ws_size >= (size_t)(ws - (char*)d_ws)) ? 1 : 0;

    const int histWords = M_ * (2048 + 2048 + 1024) + M_;       // hists + ovf
    k_zero   <<<dim3((histWords + 255) / 256), 256, 0, stream>>>(hist1, histWords);
    k_fwd    <<<dim3(M_, 5, 17),  256, 0, stream>>>(x, ll, det, hist1);   // hist1 fused
    k_sel2048<<<dim3(M_),         256, 0, stream>>>(hist1, nullptr, selBin1, rank1);
    k_hist2  <<<dim3(M_, NBY),    256, 0, stream>>>(det, selBin1, hist2, cnt, ovf, list, docap);
    k_sel2048<<<dim3(M_),         256, 0, stream>>>(hist2, rank1, selBin2, rank2);
    k_hist3  <<<dim3(M_, NBY),    256, 0, stream>>>(det, selBin1, selBin2, cnt, ovf, list, docap, hist3);
    k_sel3   <<<dim3(M_),         256, 0, stream>>>(hist3, rank2, selBin1, selBin2, tval);
    k_inv    <<<dim3(M_, 8, 16),  256, 0, stream>>>(ll, det, tval, out);
}